// Round 6
// baseline (296.253 us; speedup 1.0000x reference)
//
#include <hip/hip_runtime.h>

// DynamicAttention on MI355X (gfx950).
// Pipeline (single-pass softmaxes — scores are O(5) so exp() needs no max shift):
//   1) k_trw: W -> fp16 transposed ([n][k]) + (z==9) x -> fp16
//   2) 9 projections via fp16 MFMA GEMM (fp32 accum), LDS-bounce epilogue
//   3) v -> vt (transposed) for the PV GEMM B-operand
//   4) boundary scores: e = exp(sc) f16, compact triangular grid, LDS-bounce epilogue
//   5) per-row prefix/suffix scan -> att_mask f16 into eL; also zeroes lsc
//   6) final score: coalesced mask->LDS, dual GEMM, e->LDS, coalesced ehalf out + lsc
//   7) PV: split-K=4 GEMM ehalf@vt -> bf16 partials (alias eR), LDS-bounce epilogue
//   8) k_fin: att_weight = ehalf/lsc; att_output = sum(partials)/lsc
//
// All GEMM epilogues bounce through the (dead) staging LDS with XOR swizzle so
// global I/O is f16x8-coalesced instead of 64 scalar 2B ops per lane.

#define SS 4096
#define DD 512
#define INV_NORM 0.04419417382415922f  // 1/sqrt(512)

typedef _Float16 f16;
typedef f16 f16x8 __attribute__((ext_vector_type(8)));
typedef f16 f16x4 __attribute__((ext_vector_type(4)));
typedef float f32x4 __attribute__((ext_vector_type(4)));
typedef unsigned short ushort;

#define GAS __attribute__((address_space(1)))
#define LAS __attribute__((address_space(3)))

__device__ __forceinline__ void ldsdma16(const void* g, void* l) {
  __builtin_amdgcn_global_load_lds((const GAS void*)g, (LAS void*)l, 16, 0, 0);
}

__device__ __forceinline__ ushort f2bf(float f) {  // round-to-nearest-even bf16
  unsigned u = __float_as_uint(f);
  return (ushort)((u + 0x7FFFu + ((u >> 16) & 1u)) >> 16);
}
__device__ __forceinline__ float bf2f(ushort h) {
  return __uint_as_float((unsigned)h << 16);
}

// LDS index for logical (r,c) in a 128x128 f16 tile, 16-col-chunk XOR swizzle.
// Scatter phase: lanes of one store differ in quad=(r>>2)&3 -> 4 swizzle groups
// x 8 banks(mm/2) = 32 banks, 2 lanes/bank (free). Vector phase: 8-aligned c
// stays contiguous (XOR toggles bit 4 only).
__device__ __forceinline__ int eswz(int r, int c) {
  return r * 128 + (c ^ (((r >> 2) & 3) << 4));
}

// Stage a 128x64 f16 tile (rows x k) from row-major [*, ldk] global into LDS.
// 16B-chunk XOR swizzle: logical chunk q of row r stored at slot (q ^ (r&7)).
__device__ __forceinline__ void stage16(const f16* __restrict__ src, int ldk, f16* lds, int k0) {
  const int tid  = threadIdx.x;
  const int lane = tid & 63;
  const int wv   = tid >> 6;
  const int rb   = wv * 8 + (lane >> 3);
  const int cs   = lane & 7;
#pragma unroll
  for (int c = 0; c < 4; ++c) {
    const int r = c * 32 + rb;
    const int q = cs ^ (r & 7);
    ldsdma16(src + (size_t)r * ldk + k0 + q * 8, lds + c * 2048 + wv * 512);
  }
}

// MFMA fragment load: lane holds [m=lane&15][k=(lane>>4)*8 + 0..7].
__device__ __forceinline__ f16x8 fragld(const f16* lds, int r0, int qb) {
  const int lane = threadIdx.x & 63;
  const int r = r0 + (lane & 15);
  const int q = (qb + (lane >> 4)) ^ (r & 7);
  return *(const f16x8*)(lds + r * 64 + q * 8);
}

// Accumulate one BK=64 step: this wave's 32 rows x 128 cols (2x8 16x16 fragments).
__device__ __forceinline__ void mma64(const f16* As, const f16* Bs, f32x4 acc[2][8]) {
  const int wv = threadIdx.x >> 6;
#pragma unroll
  for (int ks = 0; ks < 2; ++ks) {
    const f16x8 a0 = fragld(As, wv * 32,      ks * 4);
    const f16x8 a1 = fragld(As, wv * 32 + 16, ks * 4);
#pragma unroll
    for (int j = 0; j < 8; ++j) {
      const f16x8 b = fragld(Bs, j * 16, ks * 4);
      acc[0][j] = __builtin_amdgcn_mfma_f32_16x16x32_f16(a0, b, acc[0][j], 0, 0, 0);
      acc[1][j] = __builtin_amdgcn_mfma_f32_16x16x32_f16(a1, b, acc[1][j], 0, 0, 0);
    }
  }
}

// Coalesced LDS tile -> global (f16x8 per thread per iter), 256 threads.
__device__ __forceinline__ void tile_out(const f16* T, f16* __restrict__ dst,
                                         int R0, int C0, int ld) {
#pragma unroll
  for (int it = 0; it < 8; ++it) {
    const int o = it * 256 + threadIdx.x;
    const int rr = o >> 4, c8 = (o & 15) * 8;
    const f16x8 v = *(const f16x8*)&T[eswz(rr, c8)];
    *(f16x8*)(dst + (size_t)(R0 + rr) * ld + C0 + c8) = v;
  }
}

// ---------------------------------------------------------------- conversions
// z<9: transpose weight z to [n][k] f16.  z==9: convert x to f16.
__global__ void k_trw(const float* w0, const float* w1, const float* w2, const float* w3,
                      const float* w4, const float* w5, const float* w6, const float* w7,
                      const float* w8, const float* __restrict__ x,
                      f16* __restrict__ wt, f16* __restrict__ xh) {
  const int z = blockIdx.z;
  if (z == 9) {
    const int b = blockIdx.y * 16 + blockIdx.x;                 // 0..255
    const int t = b * 256 + (threadIdx.y * 32 + threadIdx.x);   // 0..65535
    const size_t base = (size_t)t * 32;
#pragma unroll
    for (int u = 0; u < 8; ++u) {
      const float4 f = *(const float4*)(x + base + u * 4);
      f16x4 h = { (f16)f.x, (f16)f.y, (f16)f.z, (f16)f.w };
      *(f16x4*)(xh + base + u * 4) = h;
    }
    return;
  }
  const float* srcs[9] = {w0, w1, w2, w3, w4, w5, w6, w7, w8};
  const float* src = srcs[z];
  f16* dst = wt + (size_t)z * DD * DD;
  __shared__ float t[32][33];
  const int n0 = blockIdx.x * 32, k0 = blockIdx.y * 32;
  const int tx = threadIdx.x, ty = threadIdx.y;
#pragma unroll
  for (int i = 0; i < 32; i += 8)
    t[ty + i][tx] = src[(size_t)(k0 + ty + i) * DD + n0 + tx];
  __syncthreads();
#pragma unroll
  for (int i = 0; i < 32; i += 8)
    dst[(size_t)(n0 + ty + i) * DD + k0 + tx] = (f16)t[tx][ty + i];
}

__global__ void k_trv(const f16* __restrict__ v, f16* __restrict__ vt) {
  __shared__ f16 t[32][33];
  const int n0 = blockIdx.x * 32, s0 = blockIdx.y * 32;
  const int tx = threadIdx.x, ty = threadIdx.y;
#pragma unroll
  for (int i = 0; i < 32; i += 8)
    t[ty + i][tx] = v[(size_t)(s0 + ty + i) * DD + n0 + tx];
  __syncthreads();
#pragma unroll
  for (int i = 0; i < 32; i += 8)
    vt[(size_t)(n0 + ty + i) * SS + s0 + tx] = t[tx][ty + i];
}

// ---------------------------------------------------------------- projections
__global__ __launch_bounds__(256, 3) void k_proj(const f16* __restrict__ xh,
                                                 const f16* __restrict__ wt,
                                                 f16* __restrict__ proj) {
  __shared__ __align__(16) f16 SH[16384];
  f16* As = SH;
  f16* Bs = SH + 8192;
  const int z = blockIdx.z;
  const f16* B = wt + (size_t)z * DD * DD;
  f16* C = proj + (size_t)z * SS * DD;
  const int R0 = blockIdx.y * 128, C0 = blockIdx.x * 128;
  f32x4 acc[2][8];
#pragma unroll
  for (int i = 0; i < 2; ++i)
#pragma unroll
    for (int j = 0; j < 8; ++j) acc[i][j] = (f32x4){0.f, 0.f, 0.f, 0.f};
  for (int kb = 0; kb < DD / 64; ++kb) {
    __syncthreads();
    stage16(xh + (size_t)R0 * DD, DD, As, kb * 64);
    stage16(B  + (size_t)C0 * DD, DD, Bs, kb * 64);
    __syncthreads();
    mma64(As, Bs, acc);
  }
  const int lane = threadIdx.x & 63, wv = threadIdx.x >> 6;
  const int mm = lane & 15, quad = lane >> 4;
  __syncthreads();
#pragma unroll
  for (int i = 0; i < 2; ++i)
#pragma unroll
    for (int j = 0; j < 8; ++j)
#pragma unroll
      for (int r = 0; r < 4; ++r)
        SH[eswz(wv * 32 + i * 16 + quad * 4 + r, j * 16 + mm)] = (f16)acc[i][j][r];
  __syncthreads();
  tile_out(SH, C, R0, C0, DD);
}

// ---------------------------------------------------------------- boundaries
// Compact triangular grid: 528 tiles per dir. dir 0 = left (valid c<=r, ->eL),
// dir 1 = right (valid c>=r, ->eR).  e = exp(sc) f16, no max shift (|sc| <~ 6).
__global__ __launch_bounds__(256, 3) void k_bnd(const f16* __restrict__ proj,
                                                f16* __restrict__ eL,
                                                f16* __restrict__ eR) {
  const int t = blockIdx.x, dir = blockIdx.y;
  int rbk = (int)((sqrtf(8.f * t + 1.f) - 1.f) * 0.5f);
  while ((rbk + 1) * (rbk + 2) / 2 <= t) ++rbk;
  while (rbk * (rbk + 1) / 2 > t) --rbk;
  int jt = t - rbk * (rbk + 1) / 2;           // jt <= rbk (lower triangle)
  if (dir) { jt = 31 - jt; rbk = 31 - rbk; }  // mirror -> jt >= rbk
  __shared__ __align__(16) f16 SH[16384];
  f16* As = SH;
  f16* Bs = SH + 8192;
  const f16* q  = proj + (size_t)(dir ? 2 : 0) * SS * DD;
  const f16* kp = proj + (size_t)(dir ? 3 : 1) * SS * DD;
  const int R0 = rbk * 128, C0 = jt * 128;
  f32x4 acc[2][8];
#pragma unroll
  for (int i = 0; i < 2; ++i)
#pragma unroll
    for (int j = 0; j < 8; ++j) acc[i][j] = (f32x4){0.f, 0.f, 0.f, 0.f};
  for (int kb = 0; kb < DD / 64; ++kb) {
    __syncthreads();
    stage16(q  + (size_t)R0 * DD, DD, As, kb * 64);
    stage16(kp + (size_t)C0 * DD, DD, Bs, kb * 64);
    __syncthreads();
    mma64(As, Bs, acc);
  }
  const int lane = threadIdx.x & 63, wv = threadIdx.x >> 6;
  const int mm = lane & 15, quad = lane >> 4;
  const bool diag = (jt == rbk);
  __syncthreads();
#pragma unroll
  for (int i = 0; i < 2; ++i)
#pragma unroll
    for (int r = 0; r < 4; ++r) {
      const int rl = wv * 32 + i * 16 + quad * 4 + r;
#pragma unroll
      for (int j = 0; j < 8; ++j) {
        const int cl = j * 16 + mm;
        const float sc = acc[i][j][r] * INV_NORM;
        const bool bad = diag && (dir ? (cl < rl) : (cl > rl));
        SH[eswz(rl, cl)] = (f16)(bad ? 0.f : __expf(sc));
      }
    }
  __syncthreads();
  tile_out(SH, dir ? eR : eL, R0, C0, SS);
}

// ---------------------------------------------------------------- mask build
// One 1024-thread block per row i. Thread t owns f16x4 chunk at j=4t (coalesced).
// Also zeroes lsc[i] for k_score's atomicAdd.
__global__ __launch_bounds__(1024) void k_cumsum(f16* __restrict__ eL,
                                                 const f16* __restrict__ eR,
                                                 float* __restrict__ lsc) {
  const int i = blockIdx.x;
  const int tid = threadIdx.x, lane = tid & 63, wv = tid >> 6;  // 16 waves
  __shared__ float wsL[16], wsR[16];
  if (tid == 0) lsc[i] = 0.f;
  const int j0 = tid * 4;

  // ---- left: e values valid for j<=i
  float pl[4] = {0.f, 0.f, 0.f, 0.f};
  if (j0 <= i) {
    const f16x4 hl = *(const f16x4*)(eL + (size_t)i * SS + j0);
#pragma unroll
    for (int u = 0; u < 4; ++u) pl[u] = (j0 + u <= i) ? (float)hl[u] : 0.f;
  }
#pragma unroll
  for (int u = 1; u < 4; ++u) pl[u] += pl[u - 1];
  const float Tl = pl[3];
  float sl = Tl;
#pragma unroll
  for (int d = 1; d < 64; d <<= 1) {
    const float o = __shfl_up(sl, (unsigned)d, 64);
    if (lane >= d) sl += o;
  }
  if (lane == 63) wsL[wv] = sl;

  // ---- right: e values valid for j>=i
  float rr[4] = {0.f, 0.f, 0.f, 0.f}, pr[4];
  if (j0 + 3 >= i) {
    const f16x4 hr = *(const f16x4*)(eR + (size_t)i * SS + j0);
#pragma unroll
    for (int u = 0; u < 4; ++u) rr[u] = (j0 + u >= i) ? (float)hr[u] : 0.f;
  }
  pr[0] = rr[0];
#pragma unroll
  for (int u = 1; u < 4; ++u) pr[u] = pr[u - 1] + rr[u];
  const float Tr = pr[3];
  float sr = Tr;
#pragma unroll
  for (int d = 1; d < 64; d <<= 1) {
    const float o = __shfl_up(sr, (unsigned)d, 64);
    if (lane >= d) sr += o;
  }
  if (lane == 63) wsR[wv] = sr;

  __syncthreads();
  float offL = 0.f, totL = 0.f, offR = 0.f, totR = 0.f;
#pragma unroll
  for (int ww = 0; ww < 16; ++ww) {
    const float a = wsL[ww], b = wsR[ww];
    if (ww < wv) { offL += a; offR += b; }
    totL += a; totR += b;
  }
  const float exL = offL + sl - Tl;        // exclusive prefix before this thread
  const float exR = offR + sr - Tr;
  const float invL = 1.f / totL, invR = 1.f / totR;

  f16x4 out;
#pragma unroll
  for (int u = 0; u < 4; ++u) {
    const int j = j0 + u;
    const float cdfL = (exL + pl[u]) * invL;                 // inclusive prefix
    const float pre  = exR + pr[u];
    const float cdfR = (totR - pre + rr[u]) * invR;          // inclusive suffix
    const float m = (j < i) ? cdfL : ((j > i) ? cdfR : 1.f);
    out[u] = (f16)m;
  }
  *(f16x4*)(eL + (size_t)i * SS + j0) = out;
}

// ---------------------------------------------------------------- final scores
// sc = (qg.kg^T + (qloc.kloc^T)*mask)/norm; e=exp(sc) -> ehalf (f16); rowsum -> lsc.
// Mask staged coalesced into dead staging LDS; e bounced out the same way.
__global__ __launch_bounds__(256, 2) void k_score(const f16* __restrict__ proj,
                                                  const f16* __restrict__ mask,
                                                  f16* __restrict__ ehalf,
                                                  float* __restrict__ lsc) {
  __shared__ __align__(16) f16 SH[32768];
  f16* Ag = SH;
  f16* Bg = SH + 8192;
  f16* Al = SH + 16384;
  f16* Bl = SH + 24576;
  const int jt = blockIdx.x, rbk = blockIdx.y;
  const f16* qg = proj + (size_t)4 * SS * DD;
  const f16* kg = proj + (size_t)5 * SS * DD;
  const f16* ql = proj + (size_t)6 * SS * DD;
  const f16* kl = proj + (size_t)7 * SS * DD;
  const int R0 = rbk * 128, C0 = jt * 128;
  f32x4 ag[2][8], al[2][8];
#pragma unroll
  for (int i = 0; i < 2; ++i)
#pragma unroll
    for (int j = 0; j < 8; ++j) {
      ag[i][j] = (f32x4){0.f, 0.f, 0.f, 0.f};
      al[i][j] = (f32x4){0.f, 0.f, 0.f, 0.f};
    }
  for (int kb = 0; kb < DD / 64; ++kb) {
    __syncthreads();
    stage16(qg + (size_t)R0 * DD, DD, Ag, kb * 64);
    stage16(kg + (size_t)C0 * DD, DD, Bg, kb * 64);
    stage16(ql + (size_t)R0 * DD, DD, Al, kb * 64);
    stage16(kl + (size_t)C0 * DD, DD, Bl, kb * 64);
    __syncthreads();
    mma64(Ag, Bg, ag);
    mma64(Al, Bl, al);
  }
  const int lane = threadIdx.x & 63, wv = threadIdx.x >> 6;
  const int mm = lane & 15, quad = lane >> 4;
  // stage mask tile coalesced into SH[0:16384)
  __syncthreads();
#pragma unroll
  for (int it = 0; it < 8; ++it) {
    const int o = it * 256 + threadIdx.x;
    const int rr = o >> 4, c8 = (o & 15) * 8;
    const f16x8 m = *(const f16x8*)(mask + (size_t)(R0 + rr) * SS + C0 + c8);
    *(f16x8*)&SH[eswz(rr, c8)] = m;
  }
  __syncthreads();
  f16* TE = SH + 16384;
  float ls[2][4];
#pragma unroll
  for (int i = 0; i < 2; ++i)
#pragma unroll
    for (int r = 0; r < 4; ++r) ls[i][r] = 0.f;
#pragma unroll
  for (int i = 0; i < 2; ++i)
#pragma unroll
    for (int r = 0; r < 4; ++r) {
      const int rl = wv * 32 + i * 16 + quad * 4 + r;
#pragma unroll
      for (int j = 0; j < 8; ++j) {
        const int cl = j * 16 + mm;
        const float mk = (float)SH[eswz(rl, cl)];
        const float scv = (ag[i][j][r] + al[i][j][r] * mk) * INV_NORM;
        const float e = __expf(scv);
        TE[eswz(rl, cl)] = (f16)e;
        ls[i][r] += e;
      }
    }
#pragma unroll
  for (int d = 1; d < 16; d <<= 1)
#pragma unroll
    for (int i = 0; i < 2; ++i)
#pragma unroll
      for (int r = 0; r < 4; ++r)
        ls[i][r] += __shfl_xor(ls[i][r], d, 64);
  if (mm == 0) {
#pragma unroll
    for (int i = 0; i < 2; ++i)
#pragma unroll
      for (int r = 0; r < 4; ++r)
        atomicAdd(&lsc[R0 + wv * 32 + i * 16 + quad * 4 + r], ls[i][r]);
  }
  __syncthreads();
  tile_out(TE, ehalf, R0, C0, SS);
}

// ---------------------------------------------------------------- O = (e @ V) / lsc
// Split-K=4: blockIdx.z picks a K-chunk of 1024; bf16 partials into part[z].
__global__ __launch_bounds__(256, 4) void k_pv(const f16* __restrict__ ehalf,
                                               const f16* __restrict__ vt,
                                               ushort* __restrict__ part) {
  __shared__ __align__(16) f16 SH[16384];
  f16* As = SH;
  f16* Bs = SH + 8192;
  const int C0 = blockIdx.x * 128, R0 = blockIdx.y * 128, zk = blockIdx.z;
  f32x4 acc[2][8];
#pragma unroll
  for (int i = 0; i < 2; ++i)
#pragma unroll
    for (int j = 0; j < 8; ++j) acc[i][j] = (f32x4){0.f, 0.f, 0.f, 0.f};
  for (int kb = 0; kb < 16; ++kb) {
    const int k0 = zk * 1024 + kb * 64;
    __syncthreads();
    stage16(ehalf + (size_t)R0 * SS, SS, As, k0);
    stage16(vt    + (size_t)C0 * SS, SS, Bs, k0);
    __syncthreads();
    mma64(As, Bs, acc);
  }
  const int lane = threadIdx.x & 63, wv = threadIdx.x >> 6;
  const int mm = lane & 15, quad = lane >> 4;
  ushort* TU = (ushort*)SH;
  __syncthreads();
#pragma unroll
  for (int i = 0; i < 2; ++i)
#pragma unroll
    for (int j = 0; j < 8; ++j)
#pragma unroll
      for (int r = 0; r < 4; ++r)
        TU[eswz(wv * 32 + i * 16 + quad * 4 + r, j * 16 + mm)] = f2bf(acc[i][j][r]);
  __syncthreads();
  tile_out(SH, (f16*)(part + (size_t)zk * SS * DD), R0, C0, DD);
}

// ---------------------------------------------------------------- finalize
// blocks [0, 8192): att_weight = ehalf/lsc (f16x8 -> 2x float4)
// blocks [8192, 10240): att_output = sum(bf16 partials)/lsc (float4)
__global__ void k_fin(const f16* __restrict__ ehalf, const ushort* __restrict__ part,
                      const float* __restrict__ lsc, float* __restrict__ outw,
                      float* __restrict__ O) {
  const int bx = blockIdx.x;
  if (bx < 8192) {
    const size_t idx = ((size_t)bx * 256 + threadIdx.x) * 8;
    const int row = (int)(idx >> 12);
    const float inv = 1.f / lsc[row];
    const f16x8 h = *(const f16x8*)(ehalf + idx);
    float4 a = { (float)h[0] * inv, (float)h[1] * inv, (float)h[2] * inv, (float)h[3] * inv };
    float4 b = { (float)h[4] * inv, (float)h[5] * inv, (float)h[6] * inv, (float)h[7] * inv };
    *(float4*)(outw + idx) = a;
    *(float4*)(outw + idx + 4) = b;
  } else {
    const size_t idx = ((size_t)(bx - 8192) * 256 + threadIdx.x) * 4;
    const int row = (int)(idx >> 9);  // 512 floats per row
    float s0 = 0.f, s1 = 0.f, s2 = 0.f, s3 = 0.f;
    typedef ushort ushort4v __attribute__((ext_vector_type(4)));
#pragma unroll
    for (int p = 0; p < 4; ++p) {
      const ushort4v v = *(const ushort4v*)(part + (size_t)p * SS * DD + idx);
      s0 += bf2f(v[0]); s1 += bf2f(v[1]); s2 += bf2f(v[2]); s3 += bf2f(v[3]);
    }
    const float inv = 1.f / lsc[row];
    float4 s = { s0 * inv, s1 * inv, s2 * inv, s3 * inv };
    *(float4*)(O + idx) = s;
  }
}

// ---------------------------------------------------------------- launcher
extern "C" void kernel_launch(void* const* d_in, const int* in_sizes, int n_in,
                              void* d_out, int out_size, void* d_ws, size_t ws_size,
                              hipStream_t stream) {
  (void)in_sizes; (void)n_in; (void)out_size; (void)ws_size;
  const float* x = (const float*)d_in[0];
  const float* w[9];
  for (int i = 0; i < 9; ++i) w[i] = (const float*)d_in[1 + i];
  float* O    = (float*)d_out;            // [S,D] att_output
  float* outw = O + (size_t)SS * DD;      // [S,S] att_weight

  char* ws = (char*)d_ws;
  size_t off = 0;
  auto alloc = [&](size_t b) { void* p = ws + off; off += (b + 255) & ~(size_t)255; return p; };
  f16* xh     = (f16*)alloc((size_t)SS * DD * 2);
  f16* wt     = (f16*)alloc((size_t)9 * DD * DD * 2);
  f16* proj   = (f16*)alloc((size_t)9 * SS * DD * 2);  // ql kl qr kr qg kg qloc kloc v
  f16* vt     = (f16*)alloc((size_t)DD * SS * 2);
  f16* eL     = (f16*)alloc((size_t)SS * SS * 2);      // left probs -> att_mask (f16)
  f16* eR     = (f16*)alloc((size_t)SS * SS * 2);      // right probs; later PV partials
  f16* ehalf  = (f16*)alloc((size_t)SS * SS * 2);      // unnormalized final e in f16
  float* lsc  = (float*)alloc((size_t)SS * 4);         // final-score row sums
  ushort* part = (ushort*)eR;                          // [4][S][D] bf16 partials (eR dead)

  k_trw<<<dim3(16, 16, 10), dim3(32, 8), 0, stream>>>(w[0], w[1], w[2], w[3], w[4],
                                                      w[5], w[6], w[7], w[8], x, wt, xh);
  k_proj<<<dim3(4, 32, 9), 256, 0, stream>>>(xh, wt, proj);
  k_trv<<<dim3(16, 128), dim3(32, 8), 0, stream>>>(proj + (size_t)8 * SS * DD, vt);
  k_bnd<<<dim3(528, 2), 256, 0, stream>>>(proj, eL, eR);
  k_cumsum<<<SS, 1024, 0, stream>>>(eL, eR, lsc);
  k_score<<<dim3(32, 32), 256, 0, stream>>>(proj, eL, ehalf, lsc);
  k_pv<<<dim3(4, 32, 4), 256, 0, stream>>>(ehalf, vt, part);
  k_fin<<<10240, 256, 0, stream>>>(ehalf, part, lsc, outw, O);
}